// Round 1
// baseline (520.631 us; speedup 1.0000x reference)
//
#include <hip/hip_runtime.h>
#include <hip/hip_bf16.h>
#include <math.h>

#define IN_CH 128

// ---------------- degree histogram ----------------
__global__ __launch_bounds__(256) void deg_hist(const int* __restrict__ dst,
                                                int* __restrict__ deg, int nE) {
    int i = blockIdx.x * 256 + threadIdx.x;
    if (i < nE) atomicAdd(&deg[dst[i]], 1);
}

// ---------------- exclusive scan (single block, 1024 thr) ----------------
__global__ __launch_bounds__(1024) void scan_excl(const int* __restrict__ deg,
                                                  int* __restrict__ row_ptr, int n) {
    __shared__ int wsum[16];
    __shared__ int s_carry;
    int tid = threadIdx.x, lane = tid & 63, wid = tid >> 6;
    if (tid == 0) s_carry = 0;
    __syncthreads();
    for (int base = 0; base < n; base += 1024) {
        int i = base + tid;
        int v = (i < n) ? deg[i] : 0;
        int x = v;
        #pragma unroll
        for (int off = 1; off < 64; off <<= 1) {
            int t = __shfl_up(x, off);
            if (lane >= off) x += t;
        }
        if (lane == 63) wsum[wid] = x;
        __syncthreads();
        if (wid == 0 && lane < 16) {
            int y = wsum[lane];
            #pragma unroll
            for (int off = 1; off < 16; off <<= 1) {
                int t = __shfl_up(y, off);
                if (lane >= off) y += t;
            }
            wsum[lane] = y; // inclusive scan of wave sums
        }
        __syncthreads();
        int waveoff = (wid == 0) ? 0 : wsum[wid - 1];
        int carry = s_carry;
        if (i < n) row_ptr[i] = carry + waveoff + x - v; // exclusive
        __syncthreads();
        if (tid == 1023) s_carry = carry + wsum[15];
        __syncthreads();
    }
    if (threadIdx.x == 0) row_ptr[n] = s_carry;
}

// ---------------- scatter edges into CSR ----------------
__global__ __launch_bounds__(256) void scatter_edges(const int* __restrict__ src,
                                                     const int* __restrict__ dst,
                                                     const int* __restrict__ row_ptr,
                                                     int* __restrict__ cursor,
                                                     int* __restrict__ ssrc, int nE) {
    int i = blockIdx.x * 256 + threadIdx.x;
    if (i < nE) {
        int d = dst[i];
        int pos = row_ptr[d] + atomicAdd(&cursor[d], 1);
        ssrc[pos] = src[i];
    }
}

// ---------------- mean aggregation: one wave per node ----------------
__global__ __launch_bounds__(256) void agg_mean(const float* __restrict__ feat,
                                                const int* __restrict__ row_ptr,
                                                const int* __restrict__ ssrc,
                                                float* __restrict__ out, int nNodes) {
    int node = blockIdx.x * 4 + (threadIdx.x >> 6);
    int lane = threadIdx.x & 63;
    if (node >= nNodes) return;
    int beg = row_ptr[node], end = row_ptr[node + 1];
    float ax = 0.f, ay = 0.f;
    for (int j = beg; j < end; ++j) {
        int s = ssrc[j];
        float2 v = ((const float2*)(feat + (size_t)s * IN_CH))[lane];
        ax += v.x; ay += v.y;
    }
    float inv = 1.0f / fmaxf((float)(end - beg), 1.0f);
    float2 r; r.x = ax * inv; r.y = ay * inv;
    ((float2*)(out + (size_t)node * IN_CH))[lane] = r;
}

// ---------------- fused dual GEMM: out = act(A@Wl + bias + B@Wr) ----------------
// A,B: [nRows][128]; Wl,Wr: [128][N]; out: [nRows][N]
// 256 threads; TPR = N/32 threads per row; R = 256/TPR rows per block.
// Each thread: 32 cols as 8 float4 groups, cols = (tid%TPR)*4 + 4*TPR*j.
template <int N, int R, bool RELU>
__global__ __launch_bounds__(256) void gemm_dual(const float* __restrict__ A,
                                                 const float* __restrict__ B,
                                                 const float* __restrict__ Wl,
                                                 const float* __restrict__ Wr,
                                                 const float* __restrict__ bias,
                                                 float* __restrict__ out, int nRows) {
    constexpr int K = 128, KC = 32, TPR = N / 32;
    static_assert(R * TPR == 256, "bad tile");
    __shared__ float sWl[KC][N];
    __shared__ float sWr[KC][N];
    __shared__ float sA[R][KC + 1];
    __shared__ float sB[R][KC + 1];

    const int tid = threadIdx.x;
    const int row = tid / TPR;
    const int cbase = (tid % TPR) * 4;
    const int row0 = blockIdx.x * R;

    float acc[32];
    #pragma unroll
    for (int i = 0; i < 32; ++i) acc[i] = 0.f;

    for (int k0 = 0; k0 < K; k0 += KC) {
        // stage weights (float4, coalesced)
        constexpr int WV = KC * N / 4;
        for (int v = tid; v < WV; v += 256) {
            int kk = v / (N / 4), c4 = v % (N / 4);
            ((float4*)&sWl[kk][0])[c4] = ((const float4*)&Wl[(size_t)(k0 + kk) * N])[c4];
            ((float4*)&sWr[kk][0])[c4] = ((const float4*)&Wr[(size_t)(k0 + kk) * N])[c4];
        }
        // stage A/B row chunks
        constexpr int AE = R * KC;
        for (int e = tid; e < AE; e += 256) {
            int r = e / KC, kk = e % KC;
            int gr = row0 + r;
            float av = 0.f, bv = 0.f;
            if (gr < nRows) {
                av = A[(size_t)gr * K + k0 + kk];
                bv = B[(size_t)gr * K + k0 + kk];
            }
            sA[r][kk] = av;
            sB[r][kk] = bv;
        }
        __syncthreads();
        #pragma unroll 4
        for (int kk = 0; kk < KC; ++kk) {
            float a = sA[row][kk];
            float b = sB[row][kk];
            const float* wlrow = &sWl[kk][0];
            const float* wrrow = &sWr[kk][0];
            #pragma unroll
            for (int j = 0; j < 8; ++j) {
                float4 wl = *(const float4*)&wlrow[cbase + 4 * TPR * j];
                float4 wr = *(const float4*)&wrrow[cbase + 4 * TPR * j];
                acc[4 * j + 0] += a * wl.x; acc[4 * j + 0] += b * wr.x;
                acc[4 * j + 1] += a * wl.y; acc[4 * j + 1] += b * wr.y;
                acc[4 * j + 2] += a * wl.z; acc[4 * j + 2] += b * wr.z;
                acc[4 * j + 3] += a * wl.w; acc[4 * j + 3] += b * wr.w;
            }
        }
        __syncthreads();
    }

    int gr = row0 + row;
    if (gr < nRows) {
        float* orow = out + (size_t)gr * N;
        #pragma unroll
        for (int j = 0; j < 8; ++j) {
            int c = cbase + 4 * TPR * j;
            float4 o;
            o.x = acc[4 * j + 0] + bias[c + 0];
            o.y = acc[4 * j + 1] + bias[c + 1];
            o.z = acc[4 * j + 2] + bias[c + 2];
            o.w = acc[4 * j + 3] + bias[c + 3];
            if (RELU) {
                o.x = fmaxf(o.x, 0.f); o.y = fmaxf(o.y, 0.f);
                o.z = fmaxf(o.z, 0.f); o.w = fmaxf(o.w, 0.f);
            }
            *(float4*)&orow[c] = o;
        }
    }
}

// ---------------- log_softmax over 64 classes: one wave per row ----------------
__global__ __launch_bounds__(256) void logsm64(float* __restrict__ out, int nRows) {
    int row = blockIdx.x * 4 + (threadIdx.x >> 6);
    int lane = threadIdx.x & 63;
    if (row >= nRows) return;
    float v = out[(size_t)row * 64 + lane];
    float m = v;
    #pragma unroll
    for (int off = 32; off >= 1; off >>= 1) m = fmaxf(m, __shfl_xor(m, off));
    float e = expf(v - m);
    float s = e;
    #pragma unroll
    for (int off = 32; off >= 1; off >>= 1) s += __shfl_xor(s, off);
    out[(size_t)row * 64 + lane] = v - m - logf(s);
}

extern "C" void kernel_launch(void* const* d_in, const int* in_sizes, int n_in,
                              void* d_out, int out_size, void* d_ws, size_t ws_size,
                              hipStream_t stream) {
    const float* x   = (const float*)d_in[0];
    const int* edges = (const int*)d_in[1];
    const float* Wl1 = (const float*)d_in[2];
    const float* bl1 = (const float*)d_in[3];
    const float* Wr1 = (const float*)d_in[4];
    const float* Wl2 = (const float*)d_in[5];
    const float* bl2 = (const float*)d_in[6];
    const float* Wr2 = (const float*)d_in[7];
    float* out = (float*)d_out;

    const int nN = in_sizes[0] / IN_CH;   // 50000
    const int nE = in_sizes[1] / 2;       // 600000

    // workspace carve
    float* agg   = (float*)d_ws;                    // nN*128 f32 (reused for agg2)
    float* h     = agg + (size_t)nN * IN_CH;        // nN*128 f32
    int* degI    = (int*)(h + (size_t)nN * IN_CH);  // nN
    int* cursor  = degI + nN;                       // nN
    int* row_ptr = cursor + nN;                     // nN+1
    int* ssrc    = row_ptr + (nN + 1);              // nE

    const int* esrc = edges;
    const int* edst = edges + nE;

    hipMemsetAsync(degI, 0, sizeof(int) * (size_t)(2 * nN), stream); // degI + cursor

    deg_hist<<<(nE + 255) / 256, 256, 0, stream>>>(edst, degI, nE);
    scan_excl<<<1, 1024, 0, stream>>>(degI, row_ptr, nN);
    scatter_edges<<<(nE + 255) / 256, 256, 0, stream>>>(esrc, edst, row_ptr, cursor, ssrc, nE);

    // layer 1
    agg_mean<<<(nN + 3) / 4, 256, 0, stream>>>(x, row_ptr, ssrc, agg, nN);
    gemm_dual<128, 64, true><<<(nN + 63) / 64, 256, 0, stream>>>(agg, x, Wl1, Wr1, bl1, h, nN);

    // layer 2
    agg_mean<<<(nN + 3) / 4, 256, 0, stream>>>(h, row_ptr, ssrc, agg, nN);
    gemm_dual<64, 128, false><<<(nN + 127) / 128, 256, 0, stream>>>(agg, h, Wl2, Wr2, bl2, out, nN);

    logsm64<<<(nN + 3) / 4, 256, 0, stream>>>(out, nN);
}

// Round 2
// 359.521 us; speedup vs baseline: 1.4481x; 1.4481x over previous
//
#include <hip/hip_runtime.h>
#include <hip/hip_bf16.h>
#include <math.h>

#define IN_CH 128

typedef __attribute__((ext_vector_type(8))) short bf16x8;
typedef __attribute__((ext_vector_type(4))) float f32x4;

__device__ __forceinline__ ushort f2b(float f) {
    union { float f; uint u; } c; c.f = f;
    uint u = c.u + 0x7fff + ((c.u >> 16) & 1);   // RNE
    return (ushort)(u >> 16);
}
__device__ __forceinline__ float b2f(uint hi16) {
    union { uint u; float f; } c; c.u = hi16 << 16;
    return c.f;
}

// ---------------- x (f32) -> bf16, 8 elems/thread ----------------
__global__ __launch_bounds__(256) void x2bf(const float* __restrict__ x,
                                            ushort* __restrict__ xb, int n8) {
    int i = blockIdx.x * 256 + threadIdx.x;
    if (i >= n8) return;
    float4 a = ((const float4*)x)[2 * i];
    float4 b = ((const float4*)x)[2 * i + 1];
    union { ushort u[8]; uint4 v; } p;
    p.u[0] = f2b(a.x); p.u[1] = f2b(a.y); p.u[2] = f2b(a.z); p.u[3] = f2b(a.w);
    p.u[4] = f2b(b.x); p.u[5] = f2b(b.y); p.u[6] = f2b(b.z); p.u[7] = f2b(b.w);
    ((uint4*)xb)[i] = p.v;
}

// ---------------- weight transpose: Wt[n][k] = bf16(W[k][n]), K=128 ----------------
__global__ __launch_bounds__(256) void wtrans(const float* __restrict__ W,
                                              ushort* __restrict__ Wt, int N) {
    int i = blockIdx.x * 256 + threadIdx.x; // over 128*N
    if (i >= 128 * N) return;
    int n = i / 128, k = i % 128;
    Wt[n * 128 + k] = f2b(W[(size_t)k * N + n]);
}

// ---------------- degree histogram ----------------
__global__ __launch_bounds__(256) void deg_hist(const int* __restrict__ dst,
                                                int* __restrict__ deg, int nE) {
    int i = blockIdx.x * 256 + threadIdx.x;
    if (i < nE) atomicAdd(&deg[dst[i]], 1);
}

// ---------------- exclusive scan (single block, 1024 thr) ----------------
__global__ __launch_bounds__(1024) void scan_excl(const int* __restrict__ deg,
                                                  int* __restrict__ row_ptr, int n) {
    __shared__ int wsum[16];
    __shared__ int s_carry;
    int tid = threadIdx.x, lane = tid & 63, wid = tid >> 6;
    if (tid == 0) s_carry = 0;
    __syncthreads();
    for (int base = 0; base < n; base += 1024) {
        int i = base + tid;
        int v = (i < n) ? deg[i] : 0;
        int x = v;
        #pragma unroll
        for (int off = 1; off < 64; off <<= 1) {
            int t = __shfl_up(x, off);
            if (lane >= off) x += t;
        }
        if (lane == 63) wsum[wid] = x;
        __syncthreads();
        if (wid == 0 && lane < 16) {
            int y = wsum[lane];
            #pragma unroll
            for (int off = 1; off < 16; off <<= 1) {
                int t = __shfl_up(y, off);
                if (lane >= off) y += t;
            }
            wsum[lane] = y;
        }
        __syncthreads();
        int waveoff = (wid == 0) ? 0 : wsum[wid - 1];
        int carry = s_carry;
        if (i < n) row_ptr[i] = carry + waveoff + x - v;
        __syncthreads();
        if (tid == 1023) s_carry = carry + wsum[15];
        __syncthreads();
    }
    if (threadIdx.x == 0) row_ptr[n] = s_carry;
}

// ---------------- scatter edges into CSR ----------------
__global__ __launch_bounds__(256) void scatter_edges(const int* __restrict__ src,
                                                     const int* __restrict__ dst,
                                                     const int* __restrict__ row_ptr,
                                                     int* __restrict__ cursor,
                                                     int* __restrict__ ssrc, int nE) {
    int i = blockIdx.x * 256 + threadIdx.x;
    if (i < nE) {
        int d = dst[i];
        int pos = row_ptr[d] + atomicAdd(&cursor[d], 1);
        ssrc[pos] = src[i];
    }
}

// ---------------- mean aggregation over bf16 features: one wave per node ----------------
__global__ __launch_bounds__(256) void agg_mean_b(const ushort* __restrict__ feat,
                                                  const int* __restrict__ row_ptr,
                                                  const int* __restrict__ ssrc,
                                                  ushort* __restrict__ out, int nNodes) {
    int node = blockIdx.x * 4 + (threadIdx.x >> 6);
    int lane = threadIdx.x & 63;
    if (node >= nNodes) return;
    int beg = row_ptr[node], end = row_ptr[node + 1];
    float ax = 0.f, ay = 0.f;
    for (int jb = beg; jb < end; jb += 64) {
        int cnt = min(64, end - jb);
        int e = (jb + lane < end) ? ssrc[jb + lane] : 0;
        for (int t = 0; t < cnt; ++t) {
            int s = __shfl(e, t);
            uint v = ((const uint*)(feat + (size_t)s * IN_CH))[lane];
            ax += b2f(v & 0xffffu);
            ay += b2f(v >> 16);
        }
    }
    float inv = 1.0f / fmaxf((float)(end - beg), 1.0f);
    uint r = (uint)f2b(ax * inv) | ((uint)f2b(ay * inv) << 16);
    ((uint*)(out + (size_t)node * IN_CH))[lane] = r;
}

// ---------------- MFMA dual GEMM: out = act(A@Wl + bias + B@Wr) ----------------
// A,B: [nRows][128] bf16. WlT,WrT: [N][128] bf16 (pre-transposed). N = NT*16.
// Block: 256 thr = 4 waves, BM=64 (16 rows/wave). No LDS.
// A-frag: lane holds A[m0 + (lane&15)][(lane>>4)*8 + j + k0], 16B contiguous.
// B-frag: lane holds Wt[n][(lane>>4)*8 + j + k0] for n = nt*16 + (lane&15).
// D: out[m0 + (lane>>4)*4 + q][nt*16 + (lane&15)]  (verified C/D map).
template <int NT, bool RELU, bool OUTBF>
__global__ __launch_bounds__(256) void gemm_mfma(const ushort* __restrict__ A,
                                                 const ushort* __restrict__ B,
                                                 const ushort* __restrict__ WlT,
                                                 const ushort* __restrict__ WrT,
                                                 const float* __restrict__ bias,
                                                 void* __restrict__ outp, int nRows) {
    const int lane = threadIdx.x & 63;
    const int wave = threadIdx.x >> 6;
    const int m0 = blockIdx.x * 64 + wave * 16;
    const int r = lane & 15, g = lane >> 4;
    int row = m0 + r;
    if (row >= nRows) row = nRows - 1;           // clamp loads; stores masked
    const int kc = g * 8;

    f32x4 acc[NT];
    #pragma unroll
    for (int i = 0; i < NT; ++i) acc[i] = (f32x4){0.f, 0.f, 0.f, 0.f};

    #pragma unroll
    for (int mat = 0; mat < 2; ++mat) {
        const ushort* __restrict__ Ab = mat ? B : A;
        const ushort* __restrict__ Wb = mat ? WrT : WlT;
        const ushort* arow = Ab + (size_t)row * 128 + kc;
        #pragma unroll
        for (int k0 = 0; k0 < 128; k0 += 32) {
            bf16x8 af = *(const bf16x8*)(arow + k0);
            #pragma unroll
            for (int nt = 0; nt < NT; ++nt) {
                bf16x8 bfv = *(const bf16x8*)(Wb + (size_t)(nt * 16 + r) * 128 + k0 + kc);
                acc[nt] = __builtin_amdgcn_mfma_f32_16x16x32_bf16(af, bfv, acc[nt], 0, 0, 0);
            }
        }
    }

    constexpr int N = NT * 16;
    const int rbase = m0 + g * 4;
    #pragma unroll
    for (int nt = 0; nt < NT; ++nt) {
        float bv = bias[nt * 16 + r];
        #pragma unroll
        for (int q = 0; q < 4; ++q) {
            if (rbase + q < nRows) {
                float v = acc[nt][q] + bv;
                if (RELU) v = fmaxf(v, 0.f);
                if (OUTBF)
                    ((ushort*)outp)[(size_t)(rbase + q) * N + nt * 16 + r] = f2b(v);
                else
                    ((float*)outp)[(size_t)(rbase + q) * N + nt * 16 + r] = v;
            }
        }
    }
}

// ---------------- log_softmax over 64 classes: one wave per row ----------------
__global__ __launch_bounds__(256) void logsm64(float* __restrict__ out, int nRows) {
    int row = blockIdx.x * 4 + (threadIdx.x >> 6);
    int lane = threadIdx.x & 63;
    if (row >= nRows) return;
    float v = out[(size_t)row * 64 + lane];
    float m = v;
    #pragma unroll
    for (int off = 32; off >= 1; off >>= 1) m = fmaxf(m, __shfl_xor(m, off));
    float e = expf(v - m);
    float s = e;
    #pragma unroll
    for (int off = 32; off >= 1; off >>= 1) s += __shfl_xor(s, off);
    out[(size_t)row * 64 + lane] = v - m - logf(s);
}

extern "C" void kernel_launch(void* const* d_in, const int* in_sizes, int n_in,
                              void* d_out, int out_size, void* d_ws, size_t ws_size,
                              hipStream_t stream) {
    const float* x   = (const float*)d_in[0];
    const int* edges = (const int*)d_in[1];
    const float* Wl1 = (const float*)d_in[2];
    const float* bl1 = (const float*)d_in[3];
    const float* Wr1 = (const float*)d_in[4];
    const float* Wl2 = (const float*)d_in[5];
    const float* bl2 = (const float*)d_in[6];
    const float* Wr2 = (const float*)d_in[7];
    float* out = (float*)d_out;

    const int nN = in_sizes[0] / IN_CH;   // 50000
    const int nE = in_sizes[1] / 2;       // 600000

    // workspace carve (bf16 buffers first, 16B-aligned sizes)
    ushort* xb   = (ushort*)d_ws;                 // nN*128 bf16
    ushort* agg  = xb + (size_t)nN * IN_CH;       // nN*128 bf16
    ushort* h    = agg + (size_t)nN * IN_CH;      // nN*128 bf16
    ushort* WlT1 = h + (size_t)nN * IN_CH;        // 128*128
    ushort* WrT1 = WlT1 + 128 * 128;              // 128*128
    ushort* WlT2 = WrT1 + 128 * 128;              // 64*128
    ushort* WrT2 = WlT2 + 64 * 128;               // 64*128
    int* degI    = (int*)(WrT2 + 64 * 128);       // nN
    int* cursor  = degI + nN;                     // nN
    int* row_ptr = cursor + nN;                   // nN+1
    int* ssrc    = row_ptr + (nN + 1);            // nE

    const int* esrc = edges;
    const int* edst = edges + nE;

    hipMemsetAsync(degI, 0, sizeof(int) * (size_t)(2 * nN), stream);

    // prep (independent of CSR build)
    x2bf<<<(nN * IN_CH / 8 + 255) / 256, 256, 0, stream>>>(x, xb, nN * IN_CH / 8);
    wtrans<<<(128 * 128 + 255) / 256, 256, 0, stream>>>(Wl1, WlT1, 128);
    wtrans<<<(128 * 128 + 255) / 256, 256, 0, stream>>>(Wr1, WrT1, 128);
    wtrans<<<(128 * 64 + 255) / 256, 256, 0, stream>>>(Wl2, WlT2, 64);
    wtrans<<<(128 * 64 + 255) / 256, 256, 0, stream>>>(Wr2, WrT2, 64);

    // CSR build
    deg_hist<<<(nE + 255) / 256, 256, 0, stream>>>(edst, degI, nE);
    scan_excl<<<1, 1024, 0, stream>>>(degI, row_ptr, nN);
    scatter_edges<<<(nE + 255) / 256, 256, 0, stream>>>(esrc, edst, row_ptr, cursor, ssrc, nE);

    // layer 1
    agg_mean_b<<<(nN + 3) / 4, 256, 0, stream>>>(xb, row_ptr, ssrc, agg, nN);
    gemm_mfma<8, true, true><<<(nN + 63) / 64, 256, 0, stream>>>(agg, xb, WlT1, WrT1, bl1, h, nN);

    // layer 2
    agg_mean_b<<<(nN + 3) / 4, 256, 0, stream>>>(h, row_ptr, ssrc, agg, nN);
    gemm_mfma<4, false, false><<<(nN + 63) / 64, 256, 0, stream>>>(agg, h, WlT2, WrT2, bl2, out, nN);

    logsm64<<<(nN + 3) / 4, 256, 0, stream>>>(out, nN);
}

// Round 3
// 275.605 us; speedup vs baseline: 1.8890x; 1.3045x over previous
//
#include <hip/hip_runtime.h>
#include <hip/hip_bf16.h>
#include <math.h>

#define IN_CH 128

typedef __attribute__((ext_vector_type(8))) short bf16x8;
typedef __attribute__((ext_vector_type(4))) float f32x4;

__device__ __forceinline__ ushort f2b(float f) {
    union { float f; uint u; } c; c.f = f;
    uint u = c.u + 0x7fff + ((c.u >> 16) & 1);   // RNE
    return (ushort)(u >> 16);
}
__device__ __forceinline__ float b2f(uint hi16) {
    union { uint u; float f; } c; c.u = hi16 << 16;
    return c.f;
}

// ---------------- x (f32) -> bf16, 8 elems/thread; also zeros deg/cursor ----------------
__global__ __launch_bounds__(256) void x2bf(const float* __restrict__ x,
                                            ushort* __restrict__ xb, int n8,
                                            int* __restrict__ zbuf, int nz) {
    int i = blockIdx.x * 256 + threadIdx.x;
    if (i < nz) zbuf[i] = 0;
    if (i >= n8) return;
    float4 a = ((const float4*)x)[2 * i];
    float4 b = ((const float4*)x)[2 * i + 1];
    union { ushort u[8]; uint4 v; } p;
    p.u[0] = f2b(a.x); p.u[1] = f2b(a.y); p.u[2] = f2b(a.z); p.u[3] = f2b(a.w);
    p.u[4] = f2b(b.x); p.u[5] = f2b(b.y); p.u[6] = f2b(b.z); p.u[7] = f2b(b.w);
    ((uint4*)xb)[i] = p.v;
}

// ---------------- all 4 weight transposes in one kernel ----------------
// Wt[n][k] = bf16(W[k][n]); layer1: N=128 (2 mats), layer2: N=64 (2 mats)
__global__ __launch_bounds__(256) void wtrans_all(const float* __restrict__ Wl1,
                                                  const float* __restrict__ Wr1,
                                                  const float* __restrict__ Wl2,
                                                  const float* __restrict__ Wr2,
                                                  ushort* __restrict__ WlT1,
                                                  ushort* __restrict__ WrT1,
                                                  ushort* __restrict__ WlT2,
                                                  ushort* __restrict__ WrT2) {
    int i = blockIdx.x * 256 + threadIdx.x; // 49152 total
    if (i >= 2 * 16384 + 2 * 8192) return;
    const float* W; ushort* Wt; int N, r;
    if (i < 16384)            { W = Wl1; Wt = WlT1; N = 128; r = i; }
    else if (i < 32768)       { W = Wr1; Wt = WrT1; N = 128; r = i - 16384; }
    else if (i < 40960)       { W = Wl2; Wt = WlT2; N = 64;  r = i - 32768; }
    else                      { W = Wr2; Wt = WrT2; N = 64;  r = i - 40960; }
    int n = r / 128, k = r % 128;
    Wt[n * 128 + k] = f2b(W[(size_t)k * N + n]);
}

// ---------------- degree histogram ----------------
__global__ __launch_bounds__(256) void deg_hist(const int* __restrict__ dst,
                                                int* __restrict__ deg, int nE) {
    int i = blockIdx.x * 256 + threadIdx.x;
    if (i < nE) atomicAdd(&deg[dst[i]], 1);
}

// ---------------- hierarchical exclusive scan over deg (n <= 65536) ----------------
// k1: each block (256 thr) reduces 1024 elems -> bsum[blk]
__global__ __launch_bounds__(256) void scan_k1(const int* __restrict__ deg,
                                               int* __restrict__ bsum, int n) {
    int base = blockIdx.x * 1024 + threadIdx.x * 4;
    int s = 0;
    #pragma unroll
    for (int k = 0; k < 4; ++k) { int idx = base + k; if (idx < n) s += deg[idx]; }
    #pragma unroll
    for (int off = 1; off < 64; off <<= 1) s += __shfl_xor(s, off);
    __shared__ int ws[4];
    int lane = threadIdx.x & 63, wid = threadIdx.x >> 6;
    if (lane == 0) ws[wid] = s;
    __syncthreads();
    if (threadIdx.x == 0) bsum[blockIdx.x] = ws[0] + ws[1] + ws[2] + ws[3];
}

// k2: one wave scans <=64 block sums -> exclusive offsets; writes row_ptr[n]=nE
__global__ __launch_bounds__(64) void scan_k2(const int* __restrict__ bsum,
                                              int* __restrict__ bsumx,
                                              int* __restrict__ row_ptr, int nb,
                                              int n, int nE) {
    int lane = threadIdx.x;
    int v = (lane < nb) ? bsum[lane] : 0;
    int x = v;
    #pragma unroll
    for (int off = 1; off < 64; off <<= 1) {
        int t = __shfl_up(x, off);
        if (lane >= off) x += t;
    }
    if (lane < nb) bsumx[lane] = x - v;
    if (lane == 0) row_ptr[n] = nE;
}

// k3: each block rescans its 1024 elems + block offset -> row_ptr (exclusive)
__global__ __launch_bounds__(256) void scan_k3(const int* __restrict__ deg,
                                               const int* __restrict__ bsumx,
                                               int* __restrict__ row_ptr, int n) {
    int base = blockIdx.x * 1024 + threadIdx.x * 4;
    int v[4];
    int tsum = 0;
    #pragma unroll
    for (int k = 0; k < 4; ++k) {
        int idx = base + k;
        v[k] = (idx < n) ? deg[idx] : 0;
        tsum += v[k];
    }
    int lane = threadIdx.x & 63, wid = threadIdx.x >> 6;
    int incl = tsum;
    #pragma unroll
    for (int off = 1; off < 64; off <<= 1) {
        int t = __shfl_up(incl, off);
        if (lane >= off) incl += t;
    }
    __shared__ int ws[4];
    if (lane == 63) ws[wid] = incl;
    __syncthreads();
    int woff = 0;
    #pragma unroll
    for (int w = 0; w < 4; ++w) woff += (w < wid) ? ws[w] : 0;
    int off = bsumx[blockIdx.x] + woff + (incl - tsum);
    #pragma unroll
    for (int k = 0; k < 4; ++k) {
        int idx = base + k;
        if (idx < n) row_ptr[idx] = off;
        off += v[k];
    }
}

// ---------------- scatter edges into CSR ----------------
__global__ __launch_bounds__(256) void scatter_edges(const int* __restrict__ src,
                                                     const int* __restrict__ dst,
                                                     const int* __restrict__ row_ptr,
                                                     int* __restrict__ cursor,
                                                     int* __restrict__ ssrc, int nE) {
    int i = blockIdx.x * 256 + threadIdx.x;
    if (i < nE) {
        int d = dst[i];
        int pos = row_ptr[d] + atomicAdd(&cursor[d], 1);
        ssrc[pos] = src[i];
    }
}

// ---------------- mean aggregation over bf16 features: one wave per node ----------------
// 4x unrolled edge loop -> 4 outstanding 256B row gathers per wave
__global__ __launch_bounds__(256) void agg_mean_b(const ushort* __restrict__ feat,
                                                  const int* __restrict__ row_ptr,
                                                  const int* __restrict__ ssrc,
                                                  ushort* __restrict__ out, int nNodes) {
    int node = blockIdx.x * 4 + (threadIdx.x >> 6);
    int lane = threadIdx.x & 63;
    if (node >= nNodes) return;
    int beg = row_ptr[node], end = row_ptr[node + 1];
    float ax = 0.f, ay = 0.f;
    int j = beg;
    for (; j + 4 <= end; j += 4) {
        int s0 = ssrc[j], s1 = ssrc[j + 1], s2 = ssrc[j + 2], s3 = ssrc[j + 3];
        uint v0 = ((const uint*)(feat + (size_t)s0 * IN_CH))[lane];
        uint v1 = ((const uint*)(feat + (size_t)s1 * IN_CH))[lane];
        uint v2 = ((const uint*)(feat + (size_t)s2 * IN_CH))[lane];
        uint v3 = ((const uint*)(feat + (size_t)s3 * IN_CH))[lane];
        ax += b2f(v0 & 0xffffu) + b2f(v1 & 0xffffu) + b2f(v2 & 0xffffu) + b2f(v3 & 0xffffu);
        ay += b2f(v0 >> 16) + b2f(v1 >> 16) + b2f(v2 >> 16) + b2f(v3 >> 16);
    }
    for (; j < end; ++j) {
        int s = ssrc[j];
        uint v = ((const uint*)(feat + (size_t)s * IN_CH))[lane];
        ax += b2f(v & 0xffffu);
        ay += b2f(v >> 16);
    }
    float inv = 1.0f / fmaxf((float)(end - beg), 1.0f);
    uint r = (uint)f2b(ax * inv) | ((uint)f2b(ay * inv) << 16);
    ((uint*)(out + (size_t)node * IN_CH))[lane] = r;
}

// ---------------- MFMA dual GEMM: out = act(A@Wl + bias + B@Wr) ----------------
// A,B: [nRows][128] bf16. WlT,WrT: [N][128] bf16 (pre-transposed). N = NT*16.
// 4 waves/block, 16 rows/wave, no LDS. Optional fused log_softmax (N must be 64):
// a row's 64 values live in one 16-lane shfl group (4 regs x 16 lanes).
template <int NT, bool RELU, bool OUTBF, bool LOGSM>
__global__ __launch_bounds__(256) void gemm_mfma(const ushort* __restrict__ A,
                                                 const ushort* __restrict__ B,
                                                 const ushort* __restrict__ WlT,
                                                 const ushort* __restrict__ WrT,
                                                 const float* __restrict__ bias,
                                                 void* __restrict__ outp, int nRows) {
    const int lane = threadIdx.x & 63;
    const int wave = threadIdx.x >> 6;
    const int m0 = blockIdx.x * 64 + wave * 16;
    const int r = lane & 15, g = lane >> 4;
    int row = m0 + r;
    if (row >= nRows) row = nRows - 1;           // clamp loads; stores masked
    const int kc = g * 8;

    f32x4 acc[NT];
    #pragma unroll
    for (int i = 0; i < NT; ++i) acc[i] = (f32x4){0.f, 0.f, 0.f, 0.f};

    #pragma unroll
    for (int mat = 0; mat < 2; ++mat) {
        const ushort* __restrict__ Ab = mat ? B : A;
        const ushort* __restrict__ Wb = mat ? WrT : WlT;
        const ushort* arow = Ab + (size_t)row * 128 + kc;
        #pragma unroll
        for (int k0 = 0; k0 < 128; k0 += 32) {
            bf16x8 af = *(const bf16x8*)(arow + k0);
            #pragma unroll
            for (int nt = 0; nt < NT; ++nt) {
                bf16x8 bfv = *(const bf16x8*)(Wb + (size_t)(nt * 16 + r) * 128 + k0 + kc);
                acc[nt] = __builtin_amdgcn_mfma_f32_16x16x32_bf16(af, bfv, acc[nt], 0, 0, 0);
            }
        }
    }

    constexpr int N = NT * 16;
    const int rbase = m0 + g * 4;

    // add bias (per-column, column = nt*16 + r for all q)
    float bv[NT];
    #pragma unroll
    for (int nt = 0; nt < NT; ++nt) bv[nt] = bias[nt * 16 + r];

    if (LOGSM) {
        // per q: row rbase+q; its N=64 values are acc[0..3][q] across 16 lanes (same g)
        #pragma unroll
        for (int q = 0; q < 4; ++q) {
            float m = -1e30f;
            #pragma unroll
            for (int nt = 0; nt < NT; ++nt) m = fmaxf(m, acc[nt][q] + bv[nt]);
            #pragma unroll
            for (int off = 8; off >= 1; off >>= 1) m = fmaxf(m, __shfl_xor(m, off));
            float s = 0.f;
            #pragma unroll
            for (int nt = 0; nt < NT; ++nt) s += expf(acc[nt][q] + bv[nt] - m);
            #pragma unroll
            for (int off = 8; off >= 1; off >>= 1) s += __shfl_xor(s, off);
            float lse = m + logf(s);
            if (rbase + q < nRows) {
                float* orow = (float*)outp + (size_t)(rbase + q) * N;
                #pragma unroll
                for (int nt = 0; nt < NT; ++nt)
                    orow[nt * 16 + r] = acc[nt][q] + bv[nt] - lse;
            }
        }
    } else {
        #pragma unroll
        for (int nt = 0; nt < NT; ++nt) {
            #pragma unroll
            for (int q = 0; q < 4; ++q) {
                if (rbase + q < nRows) {
                    float v = acc[nt][q] + bv[nt];
                    if (RELU) v = fmaxf(v, 0.f);
                    if (OUTBF)
                        ((ushort*)outp)[(size_t)(rbase + q) * N + nt * 16 + r] = f2b(v);
                    else
                        ((float*)outp)[(size_t)(rbase + q) * N + nt * 16 + r] = v;
                }
            }
        }
    }
}

extern "C" void kernel_launch(void* const* d_in, const int* in_sizes, int n_in,
                              void* d_out, int out_size, void* d_ws, size_t ws_size,
                              hipStream_t stream) {
    const float* x   = (const float*)d_in[0];
    const int* edges = (const int*)d_in[1];
    const float* Wl1 = (const float*)d_in[2];
    const float* bl1 = (const float*)d_in[3];
    const float* Wr1 = (const float*)d_in[4];
    const float* Wl2 = (const float*)d_in[5];
    const float* bl2 = (const float*)d_in[6];
    const float* Wr2 = (const float*)d_in[7];
    float* out = (float*)d_out;

    const int nN = in_sizes[0] / IN_CH;   // 50000
    const int nE = in_sizes[1] / 2;       // 600000

    // workspace carve
    ushort* xb   = (ushort*)d_ws;                 // nN*128 bf16
    ushort* agg  = xb + (size_t)nN * IN_CH;       // nN*128 bf16
    ushort* h    = agg + (size_t)nN * IN_CH;      // nN*128 bf16
    ushort* WlT1 = h + (size_t)nN * IN_CH;        // 128*128
    ushort* WrT1 = WlT1 + 128 * 128;              // 128*128
    ushort* WlT2 = WrT1 + 128 * 128;              // 64*128
    ushort* WrT2 = WlT2 + 64 * 128;               // 64*128
    int* degI    = (int*)(WrT2 + 64 * 128);       // nN
    int* cursor  = degI + nN;                     // nN
    int* row_ptr = cursor + nN;                   // nN+1
    int* bsum    = row_ptr + (nN + 1);            // <=64
    int* bsumx   = bsum + 64;                     // <=64
    int* ssrc    = bsumx + 64;                    // nE

    const int* esrc = edges;
    const int* edst = edges + nE;

    const int nb = (nN + 1023) / 1024;            // 49 (<=64 required)

    // prep: bf16 convert + zero degI/cursor; weight transposes
    x2bf<<<(nN * IN_CH / 8 + 255) / 256, 256, 0, stream>>>(x, xb, nN * IN_CH / 8,
                                                           degI, 2 * nN);
    wtrans_all<<<(49152 + 255) / 256, 256, 0, stream>>>(Wl1, Wr1, Wl2, Wr2,
                                                        WlT1, WrT1, WlT2, WrT2);

    // CSR build
    deg_hist<<<(nE + 255) / 256, 256, 0, stream>>>(edst, degI, nE);
    scan_k1<<<nb, 256, 0, stream>>>(degI, bsum, nN);
    scan_k2<<<1, 64, 0, stream>>>(bsum, bsumx, row_ptr, nb, nN, nE);
    scan_k3<<<nb, 256, 0, stream>>>(degI, bsumx, row_ptr, nN);
    scatter_edges<<<(nE + 255) / 256, 256, 0, stream>>>(esrc, edst, row_ptr, cursor, ssrc, nE);

    // layer 1
    agg_mean_b<<<(nN + 3) / 4, 256, 0, stream>>>(xb, row_ptr, ssrc, agg, nN);
    gemm_mfma<8, true, true, false><<<(nN + 63) / 64, 256, 0, stream>>>(agg, xb, WlT1, WrT1, bl1, h, nN);

    // layer 2 (+ fused log_softmax)
    agg_mean_b<<<(nN + 3) / 4, 256, 0, stream>>>(h, row_ptr, ssrc, agg, nN);
    gemm_mfma<4, false, false, true><<<(nN + 63) / 64, 256, 0, stream>>>(agg, h, WlT2, WrT2, bl2, out, nN);
}

// Round 4
// 244.854 us; speedup vs baseline: 2.1263x; 1.1256x over previous
//
#include <hip/hip_runtime.h>
#include <hip/hip_bf16.h>
#include <math.h>

#define IN_CH 128

typedef __attribute__((ext_vector_type(8))) short bf16x8;
typedef __attribute__((ext_vector_type(4))) float f32x4;

__device__ __forceinline__ ushort f2b(float f) {
    union { float f; uint u; } c; c.f = f;
    uint u = c.u + 0x7fff + ((c.u >> 16) & 1);   // RNE
    return (ushort)(u >> 16);
}
__device__ __forceinline__ float b2f(uint hi16) {
    union { uint u; float f; } c; c.u = hi16 << 16;
    return c.f;
}

// ---------------- fused prep: x->bf16, zero deg, 4 weight transposes ----------------
__global__ __launch_bounds__(256) void prep(const float* __restrict__ x,
                                            ushort* __restrict__ xb, int n8,
                                            int* __restrict__ degI, int nz,
                                            const float* __restrict__ Wl1,
                                            const float* __restrict__ Wr1,
                                            const float* __restrict__ Wl2,
                                            const float* __restrict__ Wr2,
                                            ushort* __restrict__ WlT1,
                                            ushort* __restrict__ WrT1,
                                            ushort* __restrict__ WlT2,
                                            ushort* __restrict__ WrT2) {
    int i = blockIdx.x * 256 + threadIdx.x;
    if (i < nz) degI[i] = 0;
    if (i < n8) {
        float4 a = ((const float4*)x)[2 * i];
        float4 b = ((const float4*)x)[2 * i + 1];
        union { ushort u[8]; uint4 v; } p;
        p.u[0] = f2b(a.x); p.u[1] = f2b(a.y); p.u[2] = f2b(a.z); p.u[3] = f2b(a.w);
        p.u[4] = f2b(b.x); p.u[5] = f2b(b.y); p.u[6] = f2b(b.z); p.u[7] = f2b(b.w);
        ((uint4*)xb)[i] = p.v;
    } else {
        int w = i - n8;
        if (w < 2 * 16384 + 2 * 8192) {
            const float* W; ushort* Wt; int N, r;
            if (w < 16384)      { W = Wl1; Wt = WlT1; N = 128; r = w; }
            else if (w < 32768) { W = Wr1; Wt = WrT1; N = 128; r = w - 16384; }
            else if (w < 40960) { W = Wl2; Wt = WlT2; N = 64;  r = w - 32768; }
            else                { W = Wr2; Wt = WrT2; N = 64;  r = w - 40960; }
            int n = r / 128, k = r % 128;
            Wt[n * 128 + k] = f2b(W[(size_t)k * N + n]);
        }
    }
}

// ---------------- degree histogram + per-edge rank ----------------
__global__ __launch_bounds__(256) void deg_hist(const int* __restrict__ dst,
                                                int* __restrict__ deg,
                                                int* __restrict__ rank, int nE) {
    int i = blockIdx.x * 256 + threadIdx.x;
    if (i < nE) rank[i] = atomicAdd(&deg[dst[i]], 1);
}

// ---------------- scan k1: each block (256 thr) reduces 1024 elems -> bsum[blk] ----------------
__global__ __launch_bounds__(256) void scan_k1(const int* __restrict__ deg,
                                               int* __restrict__ bsum, int n) {
    int base = blockIdx.x * 1024 + threadIdx.x * 4;
    int s = 0;
    #pragma unroll
    for (int k = 0; k < 4; ++k) { int idx = base + k; if (idx < n) s += deg[idx]; }
    #pragma unroll
    for (int off = 1; off < 64; off <<= 1) s += __shfl_xor(s, off);
    __shared__ int ws[4];
    int lane = threadIdx.x & 63, wid = threadIdx.x >> 6;
    if (lane == 0) ws[wid] = s;
    __syncthreads();
    if (threadIdx.x == 0) bsum[blockIdx.x] = ws[0] + ws[1] + ws[2] + ws[3];
}

// ---------------- scan k3: block offset from bsum (inline reduce), rescan 1024 elems ----------------
__global__ __launch_bounds__(256) void scan_k3(const int* __restrict__ deg,
                                               const int* __restrict__ bsum,
                                               int* __restrict__ row_ptr, int n, int nE) {
    __shared__ int s_off;
    if (threadIdx.x < 64) {
        int v = (threadIdx.x < blockIdx.x) ? bsum[threadIdx.x] : 0;  // gridDim <= 64
        #pragma unroll
        for (int off = 32; off >= 1; off >>= 1) v += __shfl_xor(v, off);
        if (threadIdx.x == 0) s_off = v;
    }
    if (blockIdx.x == 0 && threadIdx.x == 0) row_ptr[n] = nE;
    __syncthreads();

    int base = blockIdx.x * 1024 + threadIdx.x * 4;
    int v[4];
    int tsum = 0;
    #pragma unroll
    for (int k = 0; k < 4; ++k) {
        int idx = base + k;
        v[k] = (idx < n) ? deg[idx] : 0;
        tsum += v[k];
    }
    int lane = threadIdx.x & 63, wid = threadIdx.x >> 6;
    int incl = tsum;
    #pragma unroll
    for (int off = 1; off < 64; off <<= 1) {
        int t = __shfl_up(incl, off);
        if (lane >= off) incl += t;
    }
    __shared__ int ws[4];
    if (lane == 63) ws[wid] = incl;
    __syncthreads();
    int woff = 0;
    #pragma unroll
    for (int w = 0; w < 4; ++w) woff += (w < wid) ? ws[w] : 0;
    int off = s_off + woff + (incl - tsum);
    #pragma unroll
    for (int k = 0; k < 4; ++k) {
        int idx = base + k;
        if (idx < n) row_ptr[idx] = off;
        off += v[k];
    }
}

// ---------------- scatter edges into CSR (no atomics; rank precomputed) ----------------
__global__ __launch_bounds__(256) void scatter_edges(const int* __restrict__ src,
                                                     const int* __restrict__ dst,
                                                     const int* __restrict__ row_ptr,
                                                     const int* __restrict__ rank,
                                                     int* __restrict__ ssrc, int nE) {
    int i = blockIdx.x * 256 + threadIdx.x;
    if (i < nE) {
        int d = dst[i];
        ssrc[row_ptr[d] + rank[i]] = src[i];
    }
}

// ---------------- mean aggregation: one wave per node, 2 edges per load instr ----------------
// lanes 0-31 handle even edges, 32-63 odd edges; each lane covers 4 channels (uint2=8B).
// channel group of lane l: 4*(l&31) .. 4*(l&31)+3
__global__ __launch_bounds__(256) void agg_mean_b(const ushort* __restrict__ feat,
                                                  const int* __restrict__ row_ptr,
                                                  const int* __restrict__ ssrc,
                                                  ushort* __restrict__ out, int nNodes) {
    int node = blockIdx.x * 4 + (threadIdx.x >> 6);
    int lane = threadIdx.x & 63;
    if (node >= nNodes) return;
    int beg = row_ptr[node], end = row_ptr[node + 1];
    const int half = lane >> 5;      // which edge of the pair
    const int cl = lane & 31;        // channel group
    float a0 = 0.f, a1 = 0.f, a2 = 0.f, a3 = 0.f;

    #define ACC(vv) { a0 += b2f((vv).x & 0xffffu); a1 += b2f((vv).x >> 16); \
                      a2 += b2f((vv).y & 0xffffu); a3 += b2f((vv).y >> 16); }

    int j = beg;
    for (; j + 8 <= end; j += 8) {
        int s0 = ssrc[j + 0 + half];
        int s1 = ssrc[j + 2 + half];
        int s2 = ssrc[j + 4 + half];
        int s3 = ssrc[j + 6 + half];
        uint2 v0 = ((const uint2*)(feat + (size_t)s0 * IN_CH))[cl];
        uint2 v1 = ((const uint2*)(feat + (size_t)s1 * IN_CH))[cl];
        uint2 v2 = ((const uint2*)(feat + (size_t)s2 * IN_CH))[cl];
        uint2 v3 = ((const uint2*)(feat + (size_t)s3 * IN_CH))[cl];
        ACC(v0); ACC(v1); ACC(v2); ACC(v3);
    }
    for (; j + 2 <= end; j += 2) {
        int s = ssrc[j + half];
        uint2 v = ((const uint2*)(feat + (size_t)s * IN_CH))[cl];
        ACC(v);
    }
    if (j < end && half == 0) {      // odd tail edge: 32 lanes load it
        int s = ssrc[j];
        uint2 v = ((const uint2*)(feat + (size_t)s * IN_CH))[cl];
        ACC(v);
    }
    #undef ACC

    // combine the two edge-halves
    a0 += __shfl_xor(a0, 32);
    a1 += __shfl_xor(a1, 32);
    a2 += __shfl_xor(a2, 32);
    a3 += __shfl_xor(a3, 32);

    if (half == 0) {
        float inv = 1.0f / fmaxf((float)(end - beg), 1.0f);
        uint2 r;
        r.x = (uint)f2b(a0 * inv) | ((uint)f2b(a1 * inv) << 16);
        r.y = (uint)f2b(a2 * inv) | ((uint)f2b(a3 * inv) << 16);
        ((uint2*)(out + (size_t)node * IN_CH))[cl] = r;
    }
}

// ---------------- MFMA dual GEMM: out = act(A@Wl + bias + B@Wr) ----------------
// A,B: [nRows][128] bf16. WlT,WrT: [N][128] bf16 (pre-transposed). N = NT*16.
// 4 waves/block, 16 rows/wave, no LDS. Optional fused log_softmax (N must be 64).
template <int NT, bool RELU, bool OUTBF, bool LOGSM>
__global__ __launch_bounds__(256) void gemm_mfma(const ushort* __restrict__ A,
                                                 const ushort* __restrict__ B,
                                                 const ushort* __restrict__ WlT,
                                                 const ushort* __restrict__ WrT,
                                                 const float* __restrict__ bias,
                                                 void* __restrict__ outp, int nRows) {
    const int lane = threadIdx.x & 63;
    const int wave = threadIdx.x >> 6;
    const int m0 = blockIdx.x * 64 + wave * 16;
    const int r = lane & 15, g = lane >> 4;
    int row = m0 + r;
    if (row >= nRows) row = nRows - 1;           // clamp loads; stores masked
    const int kc = g * 8;

    f32x4 acc[NT];
    #pragma unroll
    for (int i = 0; i < NT; ++i) acc[i] = (f32x4){0.f, 0.f, 0.f, 0.f};

    #pragma unroll
    for (int mat = 0; mat < 2; ++mat) {
        const ushort* __restrict__ Ab = mat ? B : A;
        const ushort* __restrict__ Wb = mat ? WrT : WlT;
        const ushort* arow = Ab + (size_t)row * 128 + kc;
        #pragma unroll
        for (int k0 = 0; k0 < 128; k0 += 32) {
            bf16x8 af = *(const bf16x8*)(arow + k0);
            #pragma unroll
            for (int nt = 0; nt < NT; ++nt) {
                bf16x8 bfv = *(const bf16x8*)(Wb + (size_t)(nt * 16 + r) * 128 + k0 + kc);
                acc[nt] = __builtin_amdgcn_mfma_f32_16x16x32_bf16(af, bfv, acc[nt], 0, 0, 0);
            }
        }
    }

    constexpr int N = NT * 16;
    const int rbase = m0 + g * 4;

    float bv[NT];
    #pragma unroll
    for (int nt = 0; nt < NT; ++nt) bv[nt] = bias[nt * 16 + r];

    if (LOGSM) {
        #pragma unroll
        for (int q = 0; q < 4; ++q) {
            float m = -1e30f;
            #pragma unroll
            for (int nt = 0; nt < NT; ++nt) m = fmaxf(m, acc[nt][q] + bv[nt]);
            #pragma unroll
            for (int off = 8; off >= 1; off >>= 1) m = fmaxf(m, __shfl_xor(m, off));
            float s = 0.f;
            #pragma unroll
            for (int nt = 0; nt < NT; ++nt) s += expf(acc[nt][q] + bv[nt] - m);
            #pragma unroll
            for (int off = 8; off >= 1; off >>= 1) s += __shfl_xor(s, off);
            float lse = m + logf(s);
            if (rbase + q < nRows) {
                float* orow = (float*)outp + (size_t)(rbase + q) * N;
                #pragma unroll
                for (int nt = 0; nt < NT; ++nt)
                    orow[nt * 16 + r] = acc[nt][q] + bv[nt] - lse;
            }
        }
    } else {
        #pragma unroll
        for (int nt = 0; nt < NT; ++nt) {
            #pragma unroll
            for (int q = 0; q < 4; ++q) {
                if (rbase + q < nRows) {
                    float v = acc[nt][q] + bv[nt];
                    if (RELU) v = fmaxf(v, 0.f);
                    if (OUTBF)
                        ((ushort*)outp)[(size_t)(rbase + q) * N + nt * 16 + r] = f2b(v);
                    else
                        ((float*)outp)[(size_t)(rbase + q) * N + nt * 16 + r] = v;
                }
            }
        }
    }
}

extern "C" void kernel_launch(void* const* d_in, const int* in_sizes, int n_in,
                              void* d_out, int out_size, void* d_ws, size_t ws_size,
                              hipStream_t stream) {
    const float* x   = (const float*)d_in[0];
    const int* edges = (const int*)d_in[1];
    const float* Wl1 = (const float*)d_in[2];
    const float* bl1 = (const float*)d_in[3];
    const float* Wr1 = (const float*)d_in[4];
    const float* Wl2 = (const float*)d_in[5];
    const float* bl2 = (const float*)d_in[6];
    const float* Wr2 = (const float*)d_in[7];
    float* out = (float*)d_out;

    const int nN = in_sizes[0] / IN_CH;   // 50000
    const int nE = in_sizes[1] / 2;       // 600000

    // workspace carve
    ushort* xb   = (ushort*)d_ws;                 // nN*128 bf16
    ushort* agg  = xb + (size_t)nN * IN_CH;       // nN*128 bf16
    ushort* h    = agg + (size_t)nN * IN_CH;      // nN*128 bf16
    ushort* WlT1 = h + (size_t)nN * IN_CH;        // 128*128
    ushort* WrT1 = WlT1 + 128 * 128;              // 128*128
    ushort* WlT2 = WrT1 + 128 * 128;              // 64*128
    ushort* WrT2 = WlT2 + 64 * 128;               // 64*128
    int* degI    = (int*)(WrT2 + 64 * 128);       // nN
    int* row_ptr = degI + nN;                     // nN+1
    int* bsum    = row_ptr + (nN + 1);            // <=64
    int* ssrc    = bsum + 64;                     // nE
    int* rank    = ssrc + nE;                     // nE

    const int* esrc = edges;
    const int* edst = edges + nE;

    const int n8 = nN * IN_CH / 8;                // 800000
    const int nb = (nN + 1023) / 1024;            // 49 (<=64 required)

    prep<<<(n8 + 49152 + 255) / 256, 256, 0, stream>>>(x, xb, n8, degI, nN,
                                                       Wl1, Wr1, Wl2, Wr2,
                                                       WlT1, WrT1, WlT2, WrT2);

    deg_hist<<<(nE + 255) / 256, 256, 0, stream>>>(edst, degI, rank, nE);
    scan_k1<<<nb, 256, 0, stream>>>(degI, bsum, nN);
    scan_k3<<<nb, 256, 0, stream>>>(degI, bsum, row_ptr, nN, nE);
    scatter_edges<<<(nE + 255) / 256, 256, 0, stream>>>(esrc, edst, row_ptr, rank, ssrc, nE);

    // layer 1
    agg_mean_b<<<(nN + 3) / 4, 256, 0, stream>>>(xb, row_ptr, ssrc, agg, nN);
    gemm_mfma<8, true, true, false><<<(nN + 63) / 64, 256, 0, stream>>>(agg, xb, WlT1, WrT1, bl1, h, nN);

    // layer 2 (+ fused log_softmax)
    agg_mean_b<<<(nN + 3) / 4, 256, 0, stream>>>(h, row_ptr, ssrc, agg, nN);
    gemm_mfma<4, false, false, true><<<(nN + 63) / 64, 256, 0, stream>>>(agg, h, WlT2, WrT2, bl2, out, nN);
}